// Round 7
// baseline (210.741 us; speedup 1.0000x reference)
//
#include <hip/hip_runtime.h>

typedef _Float16 half8 __attribute__((ext_vector_type(8)));
typedef float f32x4 __attribute__((ext_vector_type(4)));
typedef unsigned int u32x4 __attribute__((ext_vector_type(4)));

#define DD 128

#define SINKF4(v) \
  asm volatile("" ::"v"(v[0]), "v"(v[1]), "v"(v[2]), "v"(v[3]))

// Workspace layout:
//   FRAG: nch records of 8192 B. Record c, octet idx=(s*2+hl) in 0..7 at
//         offset idx*1024 + lane*16: 8 f16 of code n=c*16+(lane&15),
//         k = s*32 + (lane>>4)*8 + 0..7.  hl=0 -> hi half, hl=1 -> lo half.
//   E2NEG (after FRAG): nch * 256 B. Record c, lane slot = float
//         -(||e_n||^2) for n = c*16 + (lane&15)  (replicated over lane>>4).

__global__ void prep_kernel(const float* __restrict__ embed,
                            char* __restrict__ frag,
                            float* __restrict__ e2neg, int total) {
  int t = blockIdx.x * blockDim.x + threadIdx.x;
  if (t >= total) return;
  int lane = t & 63;
  int idx = (t >> 6) & 7;
  int c = t >> 9;
  int s = idx >> 1;
  int hl = idx & 1;
  int n = c * 16 + (lane & 15);
  int kb = s * 32 + ((lane >> 4) << 3);
  const float* src = embed + (size_t)n * DD + kb;
  _Float16* dst = (_Float16*)(frag + (size_t)c * 8192 + idx * 1024 + lane * 16);
#pragma unroll
  for (int j = 0; j < 8; ++j) {
    float v = src[j];
    _Float16 hi = (_Float16)v;
    dst[j] = hl ? (_Float16)(v - (float)hi) : hi;
  }
  if (idx == 0) {
    const float* e = embed + (size_t)n * DD;
    double acc = 0.0;
    for (int j = 0; j < DD; ++j) { double v = (double)e[j]; acc += v * v; }
    e2neg[c * 64 + lane] = (float)(-acc);
  }
}

// Shared A-fragment loader (R2-identical): 2 row-tiles, f16 hi/lo split.
__device__ __forceinline__ void load_a_frags(const float* __restrict__ x,
                                             int row0, int m16, int g,
                                             half8 ah[2][4], half8 al[2][4]) {
#pragma unroll
  for (int t = 0; t < 2; ++t) {
    const float* xrow = x + (size_t)(row0 + t * 16 + m16) * DD;
#pragma unroll
    for (int s = 0; s < 4; ++s) {
      const float* p = xrow + s * 32 + g * 8;
      f32x4 v0 = *(const f32x4*)(p);
      f32x4 v1 = *(const f32x4*)(p + 4);
#pragma unroll
      for (int j = 0; j < 4; ++j) {
        float v = v0[j];
        _Float16 hi = (_Float16)v;
        ah[t][s][j] = hi;
        al[t][s][j] = (_Float16)(v - (float)hi);
      }
#pragma unroll
      for (int j = 0; j < 4; ++j) {
        float v = v1[j];
        _Float16 hi = (_Float16)v;
        ah[t][s][4 + j] = hi;
        al[t][s][4 + j] = (_Float16)(v - (float)hi);
      }
    }
  }
}

// ---------------------------------------------------------------------------
// ABLATION V1: MFMA structure only. No per-chunk loads (b regs asm-refreshed
// so the 24-MFMA body can't be hoisted), no epilogue (acc asm-sunk).
// Isolates: MFMA issue + dependent-chain latency at 2 waves/SIMD.
// ---------------------------------------------------------------------------
__global__ __launch_bounds__(256) void abl1_mfma(const float* __restrict__ x,
                                                 const char* __restrict__ wsf,
                                                 int nch) {
  const int lane = threadIdx.x & 63;
  const int w = threadIdx.x >> 6;
  const int m16 = lane & 15;
  const int g = lane >> 4;
  const int row0 = blockIdx.x * 128 + w * 32;

  half8 ah[2][4], al[2][4];
  load_a_frags(x, row0, m16, g, ah, al);

  u32x4 braw[8];
  {
    const char* pf = wsf + lane * 16;
#pragma unroll
    for (int i = 0; i < 8; ++i) braw[i] = *(const u32x4*)(pf + i * 1024);
  }

  for (int c = 0; c < nch; ++c) {
    asm volatile("" : "+v"(braw[0]), "+v"(braw[1]), "+v"(braw[2]),
                      "+v"(braw[3]), "+v"(braw[4]), "+v"(braw[5]),
                      "+v"(braw[6]), "+v"(braw[7]));
    f32x4 acc0 = {0.f, 0.f, 0.f, 0.f};
    f32x4 acc1 = {0.f, 0.f, 0.f, 0.f};
#pragma unroll
    for (int s = 0; s < 4; ++s) {
      half8 bh = __builtin_bit_cast(half8, braw[2 * s]);
      half8 bl = __builtin_bit_cast(half8, braw[2 * s + 1]);
      acc0 = __builtin_amdgcn_mfma_f32_16x16x32_f16(ah[0][s], bh, acc0, 0, 0, 0);
      acc1 = __builtin_amdgcn_mfma_f32_16x16x32_f16(ah[1][s], bh, acc1, 0, 0, 0);
      acc0 = __builtin_amdgcn_mfma_f32_16x16x32_f16(al[0][s], bh, acc0, 0, 0, 0);
      acc1 = __builtin_amdgcn_mfma_f32_16x16x32_f16(al[1][s], bh, acc1, 0, 0, 0);
      acc0 = __builtin_amdgcn_mfma_f32_16x16x32_f16(ah[0][s], bl, acc0, 0, 0, 0);
      acc1 = __builtin_amdgcn_mfma_f32_16x16x32_f16(al[1][s], bl, acc1, 0, 0, 0);
    }
    SINKF4(acc0);
    SINKF4(acc1);
  }
}

// ---------------------------------------------------------------------------
// ABLATION V2: R2 ping-pong loads + MFMAs, epilogue replaced by sinks.
// V0 - V2 = epilogue cost; V2 - V1 = load-serialization cost.
// ---------------------------------------------------------------------------
__global__ __launch_bounds__(256) void abl2_noepi(const float* __restrict__ x,
                                                  const char* __restrict__ wsf,
                                                  const float* __restrict__ wse,
                                                  int nch) {
  const int lane = threadIdx.x & 63;
  const int w = threadIdx.x >> 6;
  const int m16 = lane & 15;
  const int g = lane >> 4;
  const int row0 = blockIdx.x * 128 + w * 32;

  half8 ah[2][4], al[2][4];
  load_a_frags(x, row0, m16, g, ah, al);

  half8 bhA[4], blA[4], bhB[4], blB[4];
  float neA, neB;

#define LOADB2(BH, BL, NE, C)                                       \
  do {                                                              \
    const char* pf = wsf + (size_t)(C)*8192 + lane * 16;            \
    const char* pf1 = pf + 4096;                                    \
    BH[0] = *(const half8*)(pf);                                    \
    BL[0] = *(const half8*)(pf + 1024);                             \
    BH[1] = *(const half8*)(pf + 2048);                             \
    BL[1] = *(const half8*)(pf + 3072);                             \
    BH[2] = *(const half8*)(pf1);                                   \
    BL[2] = *(const half8*)(pf1 + 1024);                            \
    BH[3] = *(const half8*)(pf1 + 2048);                            \
    BL[3] = *(const half8*)(pf1 + 3072);                            \
    NE = wse[(size_t)(C)*64 + lane];                                \
  } while (0)

#define COMPUTE2(BH, BL, NE)                                                 \
  do {                                                                       \
    f32x4 acc0 = {0.f, 0.f, 0.f, 0.f};                                       \
    f32x4 acc1 = {0.f, 0.f, 0.f, 0.f};                                       \
    _Pragma("unroll") for (int s = 0; s < 4; ++s) {                          \
      acc0 = __builtin_amdgcn_mfma_f32_16x16x32_f16(ah[0][s], BH[s], acc0,   \
                                                    0, 0, 0);                \
      acc1 = __builtin_amdgcn_mfma_f32_16x16x32_f16(ah[1][s], BH[s], acc1,   \
                                                    0, 0, 0);                \
      acc0 = __builtin_amdgcn_mfma_f32_16x16x32_f16(al[0][s], BH[s], acc0,   \
                                                    0, 0, 0);                \
      acc1 = __builtin_amdgcn_mfma_f32_16x16x32_f16(al[1][s], BH[s], acc1,   \
                                                    0, 0, 0);                \
      acc0 = __builtin_amdgcn_mfma_f32_16x16x32_f16(ah[0][s], BL[s], acc0,   \
                                                    0, 0, 0);                \
      acc1 = __builtin_amdgcn_mfma_f32_16x16x32_f16(ah[1][s], BL[s], acc1,   \
                                                    0, 0, 0);                \
    }                                                                        \
    SINKF4(acc0);                                                            \
    SINKF4(acc1);                                                            \
    asm volatile("" ::"v"(NE));                                              \
  } while (0)

  LOADB2(bhA, blA, neA, 0);
  for (int c = 0; c < nch; c += 2) {
    LOADB2(bhB, blB, neB, c + 1);
    COMPUTE2(bhA, blA, neA);
    if (c + 2 < nch) LOADB2(bhA, blA, neA, c + 2);
    COMPUTE2(bhB, blB, neB);
  }
#undef LOADB2
#undef COMPUTE2
}

// ---------------------------------------------------------------------------
// ABLATION V3 (full, correct): R2 with the two 12-deep dependent MFMA chains
// split into six 4-deep chains (hh/lh/hl per row-tile), summed in epilogue.
// Writes d_out, but V0 runs after and overwrites (V3 timing-only this round).
// ---------------------------------------------------------------------------
__global__ __launch_bounds__(256) void abl3_chains(
    const float* __restrict__ x, const float* __restrict__ embed,
    const char* __restrict__ wsf, const float* __restrict__ wse,
    float* __restrict__ out_q, float* __restrict__ out_i, int nch) {
  const int lane = threadIdx.x & 63;
  const int w = threadIdx.x >> 6;
  const int m16 = lane & 15;
  const int g = lane >> 4;
  const int row0 = blockIdx.x * 128 + w * 32;

  half8 ah[2][4], al[2][4];
  load_a_frags(x, row0, m16, g, ah, al);

  float bestv0[4], bestv1[4];
  int besti0[4], besti1[4];
#pragma unroll
  for (int r = 0; r < 4; ++r) {
    bestv0[r] = -__builtin_inff();
    bestv1[r] = -__builtin_inff();
    besti0[r] = 0;
    besti1[r] = 0;
  }

  half8 bhA[4], blA[4], bhB[4], blB[4];
  float neA, neB;

#define LOADB3(BH, BL, NE, C)                                       \
  do {                                                              \
    const char* pf = wsf + (size_t)(C)*8192 + lane * 16;            \
    const char* pf1 = pf + 4096;                                    \
    BH[0] = *(const half8*)(pf);                                    \
    BL[0] = *(const half8*)(pf + 1024);                             \
    BH[1] = *(const half8*)(pf + 2048);                             \
    BL[1] = *(const half8*)(pf + 3072);                             \
    BH[2] = *(const half8*)(pf1);                                   \
    BL[2] = *(const half8*)(pf1 + 1024);                            \
    BH[3] = *(const half8*)(pf1 + 2048);                            \
    BL[3] = *(const half8*)(pf1 + 3072);                            \
    NE = wse[(size_t)(C)*64 + lane];                                \
  } while (0)

#define COMPUTE3(BH, BL, NE, C)                                               \
  do {                                                                        \
    f32x4 hh0 = {0.f, 0.f, 0.f, 0.f}, hh1 = {0.f, 0.f, 0.f, 0.f};            \
    f32x4 lh0 = {0.f, 0.f, 0.f, 0.f}, lh1 = {0.f, 0.f, 0.f, 0.f};            \
    f32x4 hl0 = {0.f, 0.f, 0.f, 0.f}, hl1 = {0.f, 0.f, 0.f, 0.f};            \
    _Pragma("unroll") for (int s = 0; s < 4; ++s) {                           \
      hh0 = __builtin_amdgcn_mfma_f32_16x16x32_f16(ah[0][s], BH[s], hh0, 0,   \
                                                   0, 0);                     \
      hh1 = __builtin_amdgcn_mfma_f32_16x16x32_f16(ah[1][s], BH[s], hh1, 0,   \
                                                   0, 0);                     \
      lh0 = __builtin_amdgcn_mfma_f32_16x16x32_f16(al[0][s], BH[s], lh0, 0,   \
                                                   0, 0);                     \
      lh1 = __builtin_amdgcn_mfma_f32_16x16x32_f16(al[1][s], BH[s], lh1, 0,   \
                                                   0, 0);                     \
      hl0 = __builtin_amdgcn_mfma_f32_16x16x32_f16(ah[0][s], BL[s], hl0, 0,   \
                                                   0, 0);                     \
      hl1 = __builtin_amdgcn_mfma_f32_16x16x32_f16(ah[1][s], BL[s], hl1, 0,   \
                                                   0, 0);                     \
    }                                                                         \
    const int n_ = (C)*16 + m16;                                              \
    _Pragma("unroll") for (int r = 0; r < 4; ++r) {                           \
      float s0 = fmaf(2.f, hh0[r] + lh0[r] + hl0[r], NE);                     \
      if (s0 > bestv0[r]) { bestv0[r] = s0; besti0[r] = n_; }                 \
      float s1 = fmaf(2.f, hh1[r] + lh1[r] + hl1[r], NE);                     \
      if (s1 > bestv1[r]) { bestv1[r] = s1; besti1[r] = n_; }                 \
    }                                                                         \
  } while (0)

  LOADB3(bhA, blA, neA, 0);
  for (int c = 0; c < nch; c += 2) {
    LOADB3(bhB, blB, neB, c + 1);
    COMPUTE3(bhA, blA, neA, c);
    if (c + 2 < nch) LOADB3(bhA, blA, neA, c + 2);
    COMPUTE3(bhB, blB, neB, c + 1);
  }
#undef LOADB3
#undef COMPUTE3

#pragma unroll
  for (int off = 1; off < 16; off <<= 1) {
#pragma unroll
    for (int r = 0; r < 4; ++r) {
      float ov0 = __shfl_xor(bestv0[r], off, 64);
      int oi0 = __shfl_xor(besti0[r], off, 64);
      if (ov0 > bestv0[r] || (ov0 == bestv0[r] && oi0 < besti0[r])) {
        bestv0[r] = ov0;
        besti0[r] = oi0;
      }
      float ov1 = __shfl_xor(bestv1[r], off, 64);
      int oi1 = __shfl_xor(besti1[r], off, 64);
      if (ov1 > bestv1[r] || (ov1 == bestv1[r] && oi1 < besti1[r])) {
        bestv1[r] = ov1;
        besti1[r] = oi1;
      }
    }
  }

#pragma unroll
  for (int t = 0; t < 2; ++t) {
#pragma unroll
    for (int r = 0; r < 4; ++r) {
      const int row = row0 + t * 16 + g * 4 + r;
      const int idx = t ? besti1[r] : besti0[r];
      if (m16 == 0) out_i[row] = (float)idx;
      const f32x4* src = (const f32x4*)(embed + (size_t)idx * DD) + m16 * 2;
      f32x4* dst = (f32x4*)(out_q + (size_t)row * DD) + m16 * 2;
      dst[0] = src[0];
      dst[1] = src[1];
    }
  }
}

// ---------------------------------------------------------------------------
// V0: the round-2 kernel VERBATIM (62 us baseline). Runs LAST; owns d_out.
// ---------------------------------------------------------------------------
__global__ __launch_bounds__(256) void vq_argmin_kernel(
    const float* __restrict__ x, const float* __restrict__ embed,
    const char* __restrict__ wsf, const float* __restrict__ wse,
    float* __restrict__ out_q, float* __restrict__ out_i, int nch) {
  const int lane = threadIdx.x & 63;
  const int w = threadIdx.x >> 6;
  const int m16 = lane & 15;
  const int g = lane >> 4;
  const int row0 = blockIdx.x * 128 + w * 32;

  half8 ah[2][4], al[2][4];
  load_a_frags(x, row0, m16, g, ah, al);

  float bestv0[4], bestv1[4];
  int besti0[4], besti1[4];
#pragma unroll
  for (int r = 0; r < 4; ++r) {
    bestv0[r] = -__builtin_inff();
    bestv1[r] = -__builtin_inff();
    besti0[r] = 0;
    besti1[r] = 0;
  }

  half8 bhA[4], blA[4], bhB[4], blB[4];
  float neA, neB;

#define LOADB(BH, BL, NE, C)                                        \
  do {                                                              \
    const char* pf = wsf + (size_t)(C)*8192 + lane * 16;            \
    const char* pf1 = pf + 4096;                                    \
    BH[0] = *(const half8*)(pf);                                    \
    BL[0] = *(const half8*)(pf + 1024);                             \
    BH[1] = *(const half8*)(pf + 2048);                             \
    BL[1] = *(const half8*)(pf + 3072);                             \
    BH[2] = *(const half8*)(pf1);                                   \
    BL[2] = *(const half8*)(pf1 + 1024);                            \
    BH[3] = *(const half8*)(pf1 + 2048);                            \
    BL[3] = *(const half8*)(pf1 + 3072);                            \
    NE = wse[(size_t)(C)*64 + lane];                                \
  } while (0)

#define COMPUTE(BH, BL, NE, C)                                               \
  do {                                                                       \
    f32x4 acc0 = {0.f, 0.f, 0.f, 0.f};                                       \
    f32x4 acc1 = {0.f, 0.f, 0.f, 0.f};                                       \
    _Pragma("unroll") for (int s = 0; s < 4; ++s) {                          \
      acc0 = __builtin_amdgcn_mfma_f32_16x16x32_f16(ah[0][s], BH[s], acc0,   \
                                                    0, 0, 0);                \
      acc1 = __builtin_amdgcn_mfma_f32_16x16x32_f16(ah[1][s], BH[s], acc1,   \
                                                    0, 0, 0);                \
      acc0 = __builtin_amdgcn_mfma_f32_16x16x32_f16(al[0][s], BH[s], acc0,   \
                                                    0, 0, 0);                \
      acc1 = __builtin_amdgcn_mfma_f32_16x16x32_f16(al[1][s], BH[s], acc1,   \
                                                    0, 0, 0);                \
      acc0 = __builtin_amdgcn_mfma_f32_16x16x32_f16(ah[0][s], BL[s], acc0,   \
                                                    0, 0, 0);                \
      acc1 = __builtin_amdgcn_mfma_f32_16x16x32_f16(ah[1][s], BL[s], acc1,   \
                                                    0, 0, 0);                \
    }                                                                        \
    const int n_ = (C)*16 + m16;                                             \
    _Pragma("unroll") for (int r = 0; r < 4; ++r) {                          \
      float s0 = fmaf(2.f, acc0[r], NE);                                     \
      if (s0 > bestv0[r]) { bestv0[r] = s0; besti0[r] = n_; }                \
      float s1 = fmaf(2.f, acc1[r], NE);                                     \
      if (s1 > bestv1[r]) { bestv1[r] = s1; besti1[r] = n_; }                \
    }                                                                        \
  } while (0)

  LOADB(bhA, blA, neA, 0);
  for (int c = 0; c < nch; c += 2) {
    LOADB(bhB, blB, neB, c + 1);
    COMPUTE(bhA, blA, neA, c);
    if (c + 2 < nch) LOADB(bhA, blA, neA, c + 2);
    COMPUTE(bhB, blB, neB, c + 1);
  }
#undef LOADB
#undef COMPUTE

#pragma unroll
  for (int off = 1; off < 16; off <<= 1) {
#pragma unroll
    for (int r = 0; r < 4; ++r) {
      float ov0 = __shfl_xor(bestv0[r], off, 64);
      int oi0 = __shfl_xor(besti0[r], off, 64);
      if (ov0 > bestv0[r] || (ov0 == bestv0[r] && oi0 < besti0[r])) {
        bestv0[r] = ov0;
        besti0[r] = oi0;
      }
      float ov1 = __shfl_xor(bestv1[r], off, 64);
      int oi1 = __shfl_xor(besti1[r], off, 64);
      if (ov1 > bestv1[r] || (ov1 == bestv1[r] && oi1 < besti1[r])) {
        bestv1[r] = ov1;
        besti1[r] = oi1;
      }
    }
  }

#pragma unroll
  for (int t = 0; t < 2; ++t) {
#pragma unroll
    for (int r = 0; r < 4; ++r) {
      const int row = row0 + t * 16 + g * 4 + r;
      const int idx = t ? besti1[r] : besti0[r];
      if (m16 == 0) out_i[row] = (float)idx;
      const f32x4* src = (const f32x4*)(embed + (size_t)idx * DD) + m16 * 2;
      f32x4* dst = (f32x4*)(out_q + (size_t)row * DD) + m16 * 2;
      dst[0] = src[0];
      dst[1] = src[1];
    }
  }
}

// ---------------------------------------------------------------------------
// Fallback: exact double-precision distance, thread per row.
// ---------------------------------------------------------------------------
__global__ void vq_fallback_kernel(const float* __restrict__ x,
                                   const float* __restrict__ embed,
                                   float* __restrict__ out_q,
                                   float* __restrict__ out_i, int N, int K) {
  int row = blockIdx.x * blockDim.x + threadIdx.x;
  if (row >= N) return;
  const float* xr = x + (size_t)row * DD;
  float xv[DD];
  for (int j = 0; j < DD; ++j) xv[j] = xr[j];
  double best = -1e300;
  int bi = 0;
  for (int k = 0; k < K; ++k) {
    const float* e = embed + (size_t)k * DD;
    double acc = 0.0;
    for (int j = 0; j < DD; ++j) {
      double d = (double)xv[j] - (double)e[j];
      acc += d * d;
    }
    double sc = -acc;
    if (sc > best) { best = sc; bi = k; }
  }
  out_i[row] = (float)bi;
  for (int j = 0; j < DD; ++j)
    out_q[(size_t)row * DD + j] = embed[(size_t)bi * DD + j];
}

extern "C" void kernel_launch(void* const* d_in, const int* in_sizes, int n_in,
                              void* d_out, int out_size, void* d_ws,
                              size_t ws_size, hipStream_t stream) {
  const float* x = (const float*)d_in[0];
  const float* embed = (const float*)d_in[1];
  const int N = in_sizes[0] / DD;  // 65536 rows
  const int K = in_sizes[1] / DD;  // 1024 codes
  float* out_q = (float*)d_out;
  float* out_i = out_q + (size_t)N * DD;

  const int nch = K / 16;
  const size_t frag_bytes = (size_t)nch * 8192;
  const size_t e2_bytes = (size_t)nch * 256;
  const size_t need = frag_bytes + e2_bytes;

  if (ws_size < need || (N % 128) != 0 || (K % 16) != 0 || (nch % 2) != 0) {
    vq_fallback_kernel<<<(N + 255) / 256, 256, 0, stream>>>(x, embed, out_q,
                                                            out_i, N, K);
    return;
  }

  char* wsf = (char*)d_ws;
  float* wse = (float*)(wsf + frag_bytes);

  const int total_f = nch * 8 * 64;
  prep_kernel<<<(total_f + 255) / 256, 256, 0, stream>>>(embed, wsf, wse,
                                                         total_f);

  // Ablation dispatches (timing-only; never touch wsf/wse; V0 runs last and
  // owns every byte of d_out).
  abl1_mfma<<<N / 128, 256, 0, stream>>>(x, wsf, nch);
  abl2_noepi<<<N / 128, 256, 0, stream>>>(x, wsf, wse, nch);
  abl3_chains<<<N / 128, 256, 0, stream>>>(x, embed, wsf, wse, out_q, out_i,
                                           nch);
  vq_argmin_kernel<<<N / 128, 256, 0, stream>>>(x, embed, wsf, wse, out_q,
                                                out_i, nch);
}

// Round 8
// 68.547 us; speedup vs baseline: 3.0744x; 3.0744x over previous
//
#include <hip/hip_runtime.h>

typedef _Float16 half8 __attribute__((ext_vector_type(8)));
typedef float f32x4 __attribute__((ext_vector_type(4)));
typedef unsigned int u32x4 __attribute__((ext_vector_type(4)));

#define DD 128

// Workspace layout:
//   FRAG: nch records of 8192 B. Record c, octet idx=(s*2+hl) in 0..7 at
//         offset idx*1024 + lane*16: 8 f16 of code n=c*16+(lane&15),
//         k = s*32 + (lane>>4)*8 + 0..7.  hl=0 -> hi half, hl=1 -> lo half.
//   E2NEG (after FRAG): nch * 256 B. Record c, lane slot = float
//         -(||e_n||^2) for n = c*16 + (lane&15)  (replicated over lane>>4).

__global__ void prep_kernel(const float* __restrict__ embed,
                            char* __restrict__ frag,
                            float* __restrict__ e2neg, int total) {
  int t = blockIdx.x * blockDim.x + threadIdx.x;
  if (t >= total) return;
  int lane = t & 63;
  int idx = (t >> 6) & 7;
  int c = t >> 9;
  int s = idx >> 1;
  int hl = idx & 1;
  int n = c * 16 + (lane & 15);
  int kb = s * 32 + ((lane >> 4) << 3);
  const float* src = embed + (size_t)n * DD + kb;
  _Float16* dst = (_Float16*)(frag + (size_t)c * 8192 + idx * 1024 + lane * 16);
#pragma unroll
  for (int j = 0; j < 8; ++j) {
    float v = src[j];
    _Float16 hi = (_Float16)v;
    dst[j] = hl ? (_Float16)(v - (float)hi) : hi;
  }
  if (idx == 0) {
    const float* e = embed + (size_t)n * DD;
    double acc = 0.0;
    for (int j = 0; j < DD; ++j) { double v = (double)e[j]; acc += v * v; }
    e2neg[c * 64 + lane] = (float)(-acc);
  }
}

// Shared A-fragment loader (R2-identical): 2 row-tiles, f16 hi/lo split.
__device__ __forceinline__ void load_a_frags(const float* __restrict__ x,
                                             int row0, int m16, int g,
                                             half8 ah[2][4], half8 al[2][4]) {
#pragma unroll
  for (int t = 0; t < 2; ++t) {
    const float* xrow = x + (size_t)(row0 + t * 16 + m16) * DD;
#pragma unroll
    for (int s = 0; s < 4; ++s) {
      const float* p = xrow + s * 32 + g * 8;
      f32x4 v0 = *(const f32x4*)(p);
      f32x4 v1 = *(const f32x4*)(p + 4);
#pragma unroll
      for (int j = 0; j < 4; ++j) {
        float v = v0[j];
        _Float16 hi = (_Float16)v;
        ah[t][s][j] = hi;
        al[t][s][j] = (_Float16)(v - (float)hi);
      }
#pragma unroll
      for (int j = 0; j < 4; ++j) {
        float v = v1[j];
        _Float16 hi = (_Float16)v;
        ah[t][s][4 + j] = hi;
        al[t][s][4 + j] = (_Float16)(v - (float)hi);
      }
    }
  }
}

// ---------------------------------------------------------------------------
// Main: block = 256 thr (4 waves), block owns 64 rows, split-K over codes:
//   wave w: rows [blk*64 + (w&1)*32, +32), codebook half kh = w>>1.
// Grid = N/64 = 1024 blocks; __launch_bounds__(256,3) -> 3 waves/SIMD
// (12 waves/CU, 1.5x the TLP of rounds 2-6 — the round-7 ablation showed
// everything at 2 waves/SIMD stalls ~40us regardless of schedule).
// Per step each wave-pair stages its half's 8 KB chunk record into
// double-buffered LDS (reg-staged, issued a full step early); B fragments are
// read from LDS (8x ds_read_b128, conflict-free), e2 from LDS (broadcast,
// staged once at block start — removes R6's mid-step vmcnt(0) bug).
// Per step per wave: 24x mfma_f32_16x16x32_f16 (3-term f16 hi/lo split x
// 2 row-tiles, R2-identical order), fp32 score = fmaf(2, acc, -e2), running
// argmax. LDS merge of the two K-halves (R4-verified), 16-lane shuffle
// reduce, gather + write. C/D layout: col=lane&15, row=(lane>>4)*4+reg.
// ---------------------------------------------------------------------------
__global__ __launch_bounds__(256, 3) void vq_argmin_kernel(
    const float* __restrict__ x, const float* __restrict__ embed,
    const char* __restrict__ wsf, const float* __restrict__ wse,
    float* __restrict__ out_q, float* __restrict__ out_i, int nch) {
  const int tid = threadIdx.x;
  const int lane = tid & 63;
  const int w = tid >> 6;
  const int m16 = lane & 15;
  const int g = lane >> 4;
  const int row0 = blockIdx.x * 64 + (w & 1) * 32;
  const int kh = w >> 1;
  const int nsteps = nch >> 1;
  const int pairLane = ((w & 1) << 6) | lane;  // 0..127 within the wave pair

  __shared__ alignas(16) char lds_frag[2][2][8192];  // [buf][half][bytes]
  __shared__ float lds_e2[1024];                     // dedup -||e||^2 (nch<=64)

  // e2 -> LDS once (dedup: 16 values per chunk)
  for (int i = tid; i < nch * 16; i += 256)
    lds_e2[i] = wse[(size_t)(i >> 4) * 64 + (i & 15)];

  // A fragments for 2 row-tiles, f16 hi/lo split
  half8 ah[2][4], al[2][4];
  load_a_frags(x, row0, m16, g, ah, al);

  float bestv0[4], bestv1[4];
  int besti0[4], besti1[4];
#pragma unroll
  for (int r = 0; r < 4; ++r) {
    bestv0[r] = -__builtin_inff();
    bestv1[r] = -__builtin_inff();
    besti0[r] = 0;
    besti1[r] = 0;
  }

  // prologue: stage step 0 of this wave-pair's half into buf 0.
  // Flat 8 KB copy by 128 lanes: 4 x 16B per lane at stride 2048.
  {
    const char* gs = wsf + (size_t)(kh * nsteps) * 8192 + pairLane * 16;
    u32x4 s0 = *(const u32x4*)(gs);
    u32x4 s1 = *(const u32x4*)(gs + 2048);
    u32x4 s2 = *(const u32x4*)(gs + 4096);
    u32x4 s3 = *(const u32x4*)(gs + 6144);
    char* lw = &lds_frag[0][kh][pairLane * 16];
    *(u32x4*)(lw) = s0;
    *(u32x4*)(lw + 2048) = s1;
    *(u32x4*)(lw + 4096) = s2;
    *(u32x4*)(lw + 6144) = s3;
  }
  __syncthreads();

  for (int s = 0; s < nsteps; ++s) {
    const int buf = s & 1;
    // issue next step's global loads early (a full compute phase of cover)
    u32x4 t0, t1, t2, t3;
    const bool pre = (s + 1 < nsteps);
    if (pre) {
      const char* gs =
          wsf + (size_t)(kh * nsteps + s + 1) * 8192 + pairLane * 16;
      t0 = *(const u32x4*)(gs);
      t1 = *(const u32x4*)(gs + 2048);
      t2 = *(const u32x4*)(gs + 4096);
      t3 = *(const u32x4*)(gs + 6144);
    }

    const int chnk = kh * nsteps + s;
    const float ne_ = lds_e2[chnk * 16 + m16];

    const char* fb = &lds_frag[buf][kh][0];
    half8 bh[4], bl[4];
#pragma unroll
    for (int q = 0; q < 4; ++q) {
      bh[q] = *(const half8*)(fb + (2 * q) * 1024 + lane * 16);
      bl[q] = *(const half8*)(fb + (2 * q + 1) * 1024 + lane * 16);
    }

    f32x4 acc0 = {0.f, 0.f, 0.f, 0.f};
    f32x4 acc1 = {0.f, 0.f, 0.f, 0.f};
#pragma unroll
    for (int q = 0; q < 4; ++q) {
      acc0 = __builtin_amdgcn_mfma_f32_16x16x32_f16(ah[0][q], bh[q], acc0, 0,
                                                    0, 0);
      acc1 = __builtin_amdgcn_mfma_f32_16x16x32_f16(ah[1][q], bh[q], acc1, 0,
                                                    0, 0);
      acc0 = __builtin_amdgcn_mfma_f32_16x16x32_f16(al[0][q], bh[q], acc0, 0,
                                                    0, 0);
      acc1 = __builtin_amdgcn_mfma_f32_16x16x32_f16(al[1][q], bh[q], acc1, 0,
                                                    0, 0);
      acc0 = __builtin_amdgcn_mfma_f32_16x16x32_f16(ah[0][q], bl[q], acc0, 0,
                                                    0, 0);
      acc1 = __builtin_amdgcn_mfma_f32_16x16x32_f16(ah[1][q], bl[q], acc1, 0,
                                                    0, 0);
    }
    const int n_ = chnk * 16 + m16;
#pragma unroll
    for (int r = 0; r < 4; ++r) {
      float s0 = fmaf(2.f, acc0[r], ne_);
      if (s0 > bestv0[r]) { bestv0[r] = s0; besti0[r] = n_; }
      float s1 = fmaf(2.f, acc1[r], ne_);
      if (s1 > bestv1[r]) { bestv1[r] = s1; besti1[r] = n_; }
    }

    // write next step into the other buffer (its readers wait on the barrier)
    if (pre) {
      char* lw = &lds_frag[buf ^ 1][kh][pairLane * 16];
      *(u32x4*)(lw) = t0;
      *(u32x4*)(lw + 2048) = t1;
      *(u32x4*)(lw + 4096) = t2;
      *(u32x4*)(lw + 6144) = t3;
    }
    __syncthreads();
  }

  // cross-wave merge of the two K-halves (waves 2,3 publish; reuse frag LDS —
  // all frag reads completed before the last loop barrier).
  float* vbuf = (float*)&lds_frag[0][0][0];  // [2][64][8]
  int* ibuf = (int*)&lds_frag[0][1][0];      // [2][64][8]
  if (w >= 2) {
    float* vb = vbuf + ((w - 2) * 64 + lane) * 8;
    int* ib = ibuf + ((w - 2) * 64 + lane) * 8;
#pragma unroll
    for (int r = 0; r < 4; ++r) {
      vb[r] = bestv0[r];
      vb[4 + r] = bestv1[r];
      ib[r] = besti0[r];
      ib[4 + r] = besti1[r];
    }
  }
  __syncthreads();
  if (w >= 2) return;

  {
    const float* vb = vbuf + (w * 64 + lane) * 8;
    const int* ib = ibuf + (w * 64 + lane) * 8;
#pragma unroll
    for (int r = 0; r < 4; ++r) {
      float pv0 = vb[r];
      int pi0 = ib[r];
      if (pv0 > bestv0[r] || (pv0 == bestv0[r] && pi0 < besti0[r])) {
        bestv0[r] = pv0;
        besti0[r] = pi0;
      }
      float pv1 = vb[4 + r];
      int pi1 = ib[4 + r];
      if (pv1 > bestv1[r] || (pv1 == bestv1[r] && pi1 < besti1[r])) {
        bestv1[r] = pv1;
        besti1[r] = pi1;
      }
    }
  }

  // reduce across the 16 lanes sharing each C row; smaller index on tie
#pragma unroll
  for (int off = 1; off < 16; off <<= 1) {
#pragma unroll
    for (int r = 0; r < 4; ++r) {
      float ov0 = __shfl_xor(bestv0[r], off, 64);
      int oi0 = __shfl_xor(besti0[r], off, 64);
      if (ov0 > bestv0[r] || (ov0 == bestv0[r] && oi0 < besti0[r])) {
        bestv0[r] = ov0;
        besti0[r] = oi0;
      }
      float ov1 = __shfl_xor(bestv1[r], off, 64);
      int oi1 = __shfl_xor(besti1[r], off, 64);
      if (ov1 > bestv1[r] || (ov1 == bestv1[r] && oi1 < besti1[r])) {
        bestv1[r] = ov1;
        besti1[r] = oi1;
      }
    }
  }

  // outputs: index (as float) + gathered code row (16 lanes x 8 floats)
#pragma unroll
  for (int t = 0; t < 2; ++t) {
#pragma unroll
    for (int r = 0; r < 4; ++r) {
      const int row = row0 + t * 16 + g * 4 + r;
      const int idx = t ? besti1[r] : besti0[r];
      if (m16 == 0) out_i[row] = (float)idx;
      const f32x4* src = (const f32x4*)(embed + (size_t)idx * DD) + m16 * 2;
      f32x4* dst = (f32x4*)(out_q + (size_t)row * DD) + m16 * 2;
      dst[0] = src[0];
      dst[1] = src[1];
    }
  }
}

// ---------------------------------------------------------------------------
// Fallback: exact double-precision distance, thread per row.
// ---------------------------------------------------------------------------
__global__ void vq_fallback_kernel(const float* __restrict__ x,
                                   const float* __restrict__ embed,
                                   float* __restrict__ out_q,
                                   float* __restrict__ out_i, int N, int K) {
  int row = blockIdx.x * blockDim.x + threadIdx.x;
  if (row >= N) return;
  const float* xr = x + (size_t)row * DD;
  float xv[DD];
  for (int j = 0; j < DD; ++j) xv[j] = xr[j];
  double best = -1e300;
  int bi = 0;
  for (int k = 0; k < K; ++k) {
    const float* e = embed + (size_t)k * DD;
    double acc = 0.0;
    for (int j = 0; j < DD; ++j) {
      double d = (double)xv[j] - (double)e[j];
      acc += d * d;
    }
    double sc = -acc;
    if (sc > best) { best = sc; bi = k; }
  }
  out_i[row] = (float)bi;
  for (int j = 0; j < DD; ++j)
    out_q[(size_t)row * DD + j] = embed[(size_t)bi * DD + j];
}

extern "C" void kernel_launch(void* const* d_in, const int* in_sizes, int n_in,
                              void* d_out, int out_size, void* d_ws,
                              size_t ws_size, hipStream_t stream) {
  const float* x = (const float*)d_in[0];
  const float* embed = (const float*)d_in[1];
  const int N = in_sizes[0] / DD;  // 65536 rows
  const int K = in_sizes[1] / DD;  // 1024 codes
  float* out_q = (float*)d_out;
  float* out_i = out_q + (size_t)N * DD;

  const int nch = K / 16;
  const size_t frag_bytes = (size_t)nch * 8192;
  const size_t e2_bytes = (size_t)nch * 256;
  const size_t need = frag_bytes + e2_bytes;

  if (ws_size < need || (N % 64) != 0 || (K % 16) != 0 || (nch % 2) != 0 ||
      nch > 64) {
    vq_fallback_kernel<<<(N + 255) / 256, 256, 0, stream>>>(x, embed, out_q,
                                                            out_i, N, K);
    return;
  }

  char* wsf = (char*)d_ws;
  float* wse = (float*)(wsf + frag_bytes);

  const int total_f = nch * 8 * 64;
  prep_kernel<<<(total_f + 255) / 256, 256, 0, stream>>>(embed, wsf, wse,
                                                         total_f);
  vq_argmin_kernel<<<N / 64, 256, 0, stream>>>(x, embed, wsf, wse, out_q,
                                               out_i, nch);
}